// Round 7
// baseline (1296.943 us; speedup 1.0000x reference)
//
#include <hip/hip_runtime.h>

#define NSUP 4096
#define NTOT 8192
#define DIN  512
#define DEMB 256
#define NCLS 64
#define PKS  8      // prop K-splits

typedef __attribute__((ext_vector_type(8))) short bf16x8;
typedef __attribute__((ext_vector_type(4))) float f32x4;
typedef __attribute__((ext_vector_type(4))) unsigned int u32x4;

__device__ inline unsigned short f2bf(float x) {
  unsigned int u = __builtin_bit_cast(unsigned int, x);
  u += 0x7FFFu + ((u >> 16) & 1u);   // RNE
  return (unsigned short)(u >> 16);
}
__device__ inline float bf2f(unsigned short h) {
  unsigned int u = ((unsigned int)h) << 16;
  return __builtin_bit_cast(float, u);
}

// fragment-major layouts:
// e[Hi/Lo]F: [row>>4][col>>5][(row&15)+16*((col>>3)&3)][col&7]
// LtF:       [i>>5][c>>4][(c&15)+16*((i>>3)&3)][i&7]
__device__ inline size_t lfrag(int i, int c) {
  return (((size_t)(i >> 5) * (NCLS / 16) + (c >> 4)) * 64 +
          (c & 15) + 16 * ((i >> 3) & 3)) * 8 + (i & 7);
}

// ---------- 1a) split X (fp32 -> bf16 hi/lo) into fragment-major [8192][512] ----------
__global__ __launch_bounds__(256) void splitX(
    const float* __restrict__ support, const float* __restrict__ query,
    unsigned short* __restrict__ XhF, unsigned short* __restrict__ XlF) {
  int w = threadIdx.x >> 6, lane = threadIdx.x & 63;
  int row = blockIdx.x * 4 + w;
  const float* X = (row < NSUP) ? (support + (size_t)row * DIN)
                                : (query + (size_t)(row - NSUP) * DIN);
  const float4* p = (const float4*)(X + lane * 8);
  float4 a = p[0], b = p[1];
  float v[8] = {a.x, a.y, a.z, a.w, b.x, b.y, b.z, b.w};
  bf16x8 hv, lv;
  #pragma unroll
  for (int j = 0; j < 8; j++) {
    unsigned short h = f2bf(v[j]);
    hv[j] = (short)h;
    lv[j] = (short)f2bf(v[j] - bf2f(h));
  }
  size_t off = (((size_t)(row >> 4) * (DIN / 32) + (lane >> 2)) * 64 +
                (row & 15) + 16 * (lane & 3)) * 8;
  *reinterpret_cast<bf16x8*>(XhF + off) = hv;
  *reinterpret_cast<bf16x8*>(XlF + off) = lv;
}

// ---------- 1b) split W [512][256] into B-side fragment-major ----------
__global__ __launch_bounds__(256) void splitW(
    const float* __restrict__ W, unsigned short* __restrict__ WhF,
    unsigned short* __restrict__ WlF) {
  int idx = blockIdx.x * 256 + threadIdx.x;
  int n = idx & 255, kb8 = idx >> 8;       // kb8 = k-octet 0..63
  bf16x8 hv, lv;
  #pragma unroll
  for (int j = 0; j < 8; j++) {
    float v = W[(size_t)(kb8 * 8 + j) * DEMB + n];
    unsigned short h = f2bf(v);
    hv[j] = (short)h;
    lv[j] = (short)f2bf(v - bf2f(h));
  }
  size_t off = (((size_t)(n >> 4) * (DIN / 32) + (kb8 >> 2)) * 64 +
                (n & 15) + 16 * (kb8 & 3)) * 8;
  *reinterpret_cast<bf16x8*>(WhF + off) = hv;
  *reinterpret_cast<bf16x8*>(WlF + off) = lv;
}

// ---------- 1c) emb = X @ W via 4-product split-bf16 MFMA -> ehiF/eloF frag-major ----------
__global__ __launch_bounds__(256) void emb_mfma(
    const unsigned short* __restrict__ XhF, const unsigned short* __restrict__ XlF,
    const unsigned short* __restrict__ WhF, const unsigned short* __restrict__ WlF,
    unsigned short* __restrict__ ehiF, unsigned short* __restrict__ eloF) {
  __shared__ float lds[4][16][65];
  int lane = threadIdx.x & 63, w = threadIdx.x >> 6;
  int l15 = lane & 15, lg = lane >> 4;
  int rowblk0 = blockIdx.x * 2;            // 32 rows per block
  f32x4 acc[2][4] = {};
  for (int kb = 0; kb < DIN / 32; kb++) {
    bf16x8 ah[2], al[2], bh[4], bl[4];
    #pragma unroll
    for (int fm = 0; fm < 2; fm++) {
      size_t o = (((size_t)(rowblk0 + fm) * (DIN / 32) + kb) * 64 + lane) * 8;
      ah[fm] = *reinterpret_cast<const bf16x8*>(XhF + o);
      al[fm] = *reinterpret_cast<const bf16x8*>(XlF + o);
    }
    #pragma unroll
    for (int fn = 0; fn < 4; fn++) {
      size_t o = (((size_t)(w * 4 + fn) * (DIN / 32) + kb) * 64 + lane) * 8;
      bh[fn] = *reinterpret_cast<const bf16x8*>(WhF + o);
      bl[fn] = *reinterpret_cast<const bf16x8*>(WlF + o);
    }
    #pragma unroll
    for (int fm = 0; fm < 2; fm++)
      #pragma unroll
      for (int fn = 0; fn < 4; fn++) {
        acc[fm][fn] = __builtin_amdgcn_mfma_f32_16x16x32_bf16(ah[fm], bh[fn], acc[fm][fn], 0, 0, 0);
        acc[fm][fn] = __builtin_amdgcn_mfma_f32_16x16x32_bf16(ah[fm], bl[fn], acc[fm][fn], 0, 0, 0);
        acc[fm][fn] = __builtin_amdgcn_mfma_f32_16x16x32_bf16(al[fm], bh[fn], acc[fm][fn], 0, 0, 0);
        acc[fm][fn] = __builtin_amdgcn_mfma_f32_16x16x32_bf16(al[fm], bl[fn], acc[fm][fn], 0, 0, 0);
      }
  }
  // C/D (col=l15,row=lg*4+r) -> fragment-major via LDS permute
  for (int fm = 0; fm < 2; fm++) {
    #pragma unroll
    for (int fn = 0; fn < 4; fn++)
      #pragma unroll
      for (int r = 0; r < 4; r++)
        lds[w][lg * 4 + r][fn * 16 + l15] = acc[fm][fn][r];
    __syncthreads();
    #pragma unroll
    for (int cb = 0; cb < 2; cb++) {
      const float* src = &lds[w][l15][cb * 32 + lg * 8];
      bf16x8 hv, lv;
      #pragma unroll
      for (int j = 0; j < 8; j++) {
        float v = src[j];
        unsigned short h = f2bf(v);
        hv[j] = (short)h;
        lv[j] = (short)f2bf(v - bf2f(h));
      }
      size_t off = (((size_t)(rowblk0 + fm) * (DEMB / 32) + w * 2 + cb) * 64 + lane) * 8;
      *reinterpret_cast<bf16x8*>(ehiF + off) = hv;
      *reinterpret_cast<bf16x8*>(eloF + off) = lv;
    }
    __syncthreads();
  }
}

// ---------- 2) similarity: tri-linearized grid + XCD swizzle -> Apk both triangles ----------
__global__ __launch_bounds__(256) void sim_kernel(
    const unsigned short* __restrict__ ehiF, const unsigned short* __restrict__ eloF,
    unsigned int* __restrict__ Apk) {
  // 2080 upper-tri tiles; bijective XCD swizzle (2080 = 8*260), then inverse-triangular
  int bid = (blockIdx.x & 7) * 260 + (blockIdx.x >> 3);
  int r = 2079 - bid;
  int j = (int)((sqrtf((float)(8 * r + 1)) - 1.0f) * 0.5f);
  while ((j + 1) * (j + 2) / 2 <= r) ++j;
  while (j * (j + 1) / 2 > r) --j;
  int by = 63 - j;
  int bx = 63 - (r - j * (j + 1) / 2);

  __shared__ unsigned short LTn[128][8];     // normal bit-rows (ushort per 16 cols)
  __shared__ unsigned short LTt[128][8];     // transposed
  int lane = threadIdx.x & 63;
  int w = threadIdx.x >> 6, wm = w >> 1, wn = w & 1;
  int l15 = lane & 15, lg = lane >> 4;
  int arb = by * 8 + wm * 4, brb = bx * 8 + wn * 4;

  f32x4 acc[4][4] = {};
  for (int kb = 0; kb < DEMB / 32; kb++) {
    bf16x8 bh[4], bl[4];
    #pragma unroll
    for (int fn = 0; fn < 4; fn++) {
      size_t o = (((size_t)(brb + fn) * (DEMB / 32) + kb) * 64 + lane) * 8;
      bh[fn] = *reinterpret_cast<const bf16x8*>(ehiF + o);
      bl[fn] = *reinterpret_cast<const bf16x8*>(eloF + o);
    }
    #pragma unroll
    for (int fm = 0; fm < 4; fm++) {
      size_t o = (((size_t)(arb + fm) * (DEMB / 32) + kb) * 64 + lane) * 8;
      bf16x8 ah = *reinterpret_cast<const bf16x8*>(ehiF + o);
      bf16x8 al = *reinterpret_cast<const bf16x8*>(eloF + o);
      #pragma unroll
      for (int fn = 0; fn < 4; fn++) {
        acc[fm][fn] = __builtin_amdgcn_mfma_f32_16x16x32_bf16(ah, bh[fn], acc[fm][fn], 0, 0, 0);
        acc[fm][fn] = __builtin_amdgcn_mfma_f32_16x16x32_bf16(ah, bl[fn], acc[fm][fn], 0, 0, 0);
        acc[fm][fn] = __builtin_amdgcn_mfma_f32_16x16x32_bf16(al, bh[fn], acc[fm][fn], 0, 0, 0);
      }
    }
  }
  // threshold + ballot; build normal and transposed bit-rows in LDS
  #pragma unroll
  for (int fm = 0; fm < 4; fm++)
    #pragma unroll
    for (int fn = 0; fn < 4; fn++) {
      unsigned long long bal[4];
      #pragma unroll
      for (int r4 = 0; r4 < 4; r4++) {
        bal[r4] = __ballot(acc[fm][fn][r4] > 0.5f);
        if (l15 == 0)
          LTn[wm * 64 + fm * 16 + lg * 4 + r4][wn * 4 + fn] =
              (unsigned short)(bal[r4] >> (lg * 16));
      }
      unsigned int tv = 0;
      #pragma unroll
      for (int p = 0; p < 16; p++) {
        unsigned int half = (unsigned int)(bal[p & 3] >> ((p >> 2) * 16));
        tv |= ((half >> l15) & 1u) << p;
      }
      if (lg == 0) LTt[wn * 64 + fn * 16 + l15][wm * 4 + fm] = (unsigned short)tv;
    }
  __syncthreads();
  // assemble Apk dwords: dword(rowblk,S4,lane={row&15,lg}) byte t = bits k=S4*128+t*32+lg*8
  #pragma unroll
  for (int pass = 0; pass < 2; pass++) {
    int idx = pass * 256 + threadIdx.x;      // 0..511
    int rb4 = idx >> 6, ln = idx & 63;
    int lr = rb4 * 16 + (ln & 15), Lg = ln >> 4;
    unsigned int d = 0, d2 = 0;
    #pragma unroll
    for (int t = 0; t < 4; t++) {
      int bix = t * 4 + Lg;
      unsigned int u = LTn[lr][bix >> 1];
      d |= ((u >> ((bix & 1) * 8)) & 0xffu) << (t * 8);
      unsigned int u2 = LTt[lr][bix >> 1];
      d2 |= ((u2 >> ((bix & 1) * 8)) & 0xffu) << (t * 8);
    }
    Apk[((size_t)(by * 8 + rb4) * 64 + bx) * 64 + ln] = d;
    Apk[((size_t)(bx * 8 + rb4) * 64 + by) * 64 + ln] = d2;
  }
}

// ---------- 3) rdeg = 1/popcount, straight from Apk (coalesced) ----------
__global__ __launch_bounds__(256) void degree_kernel(
    const unsigned int* __restrict__ Apk, float* __restrict__ rdeg) {
  __shared__ int dg[4][16];
  int rowblk = blockIdx.x;
  int w = threadIdx.x >> 6, lane = threadIdx.x & 63;
  const unsigned int* base = Apk + (size_t)rowblk * 4096;
  int cnt = 0;
  #pragma unroll
  for (int s = 0; s < 16; s++) cnt += __popc(base[(w * 16 + s) * 64 + lane]);
  cnt += __shfl_xor(cnt, 16);
  cnt += __shfl_xor(cnt, 32);
  if (lane < 16) dg[w][lane] = cnt;
  __syncthreads();
  if (threadIdx.x < 16) {
    int c = dg[0][threadIdx.x] + dg[1][threadIdx.x] + dg[2][threadIdx.x] + dg[3][threadIdx.x];
    rdeg[rowblk * 16 + threadIdx.x] = (c == 0) ? 1.f : 1.f / (float)c;
  }
}

// ---------- 4) label init + counter zeroing ----------
__global__ __launch_bounds__(256) void init_labels(
    const int* __restrict__ slab, float* __restrict__ labels,
    unsigned short* __restrict__ LtF, int* __restrict__ cnt) {
  int idx = blockIdx.x * 256 + threadIdx.x;
  if (idx < 10 * 64) cnt[idx] = 0;
  int i = idx >> 6, c = idx & 63;
  float v = 0.f;
  if (i < NSUP && slab[i] == c) v = 1.f;
  labels[idx] = v;
  LtF[lfrag(i, c)] = f2bf(v);
}

// ---------- 5) prop: M-register-blocked K-split GEMM + fenced last-block epilogue ----------
// grid dim3(PKS, 64): ks = blockIdx.x (XCD-resident LtF chunk), rg = blockIdx.y (128 rows)
// block 512 thr = 8 waves (wr 2 x wk 4); wave = 4 rowblks (64 rows) x 256 K
#define RED(k, row, col) red[k][row][(col) ^ ((((row) >> 2) & 3) << 4)]
__global__ __launch_bounds__(512, 4) void prop_kernel(
    const unsigned int* __restrict__ Apk, const unsigned short* __restrict__ LtinF,
    const float* __restrict__ rdeg, float* __restrict__ labels,
    unsigned short* __restrict__ LtoutF, float* __restrict__ outq,
    float* __restrict__ Cpart, int* __restrict__ cnt, int last) {
  __shared__ float red[4][64][64];          // 64 KB, col-swizzled
  int lane = threadIdx.x & 63;
  int w = threadIdx.x >> 6;
  int wr = w >> 2, wk = w & 3;
  int l15 = lane & 15, lg = lane >> 4;
  int ks = blockIdx.x, rg = blockIdx.y;
  int rb0 = rg * 8 + wr * 4;                // first of 4 rowblks
  int s4base = ks * 8 + wk * 2;             // 2 S4 units (128 K each) per wave

  f32x4 acc[4][4] = {};
  #pragma unroll
  for (int s4 = 0; s4 < 2; s4++) {
    unsigned int ad[4];
    #pragma unroll
    for (int rb = 0; rb < 4; rb++)
      ad[rb] = Apk[((size_t)(rb0 + rb) * 64 + (s4base + s4)) * 64 + lane];
    #pragma unroll
    for (int t = 0; t < 4; t++) {
      int kstep = (s4base + s4) * 4 + t;
      bf16x8 b[4];
      #pragma unroll
      for (int fn = 0; fn < 4; fn++)
        b[fn] = *reinterpret_cast<const bf16x8*>(
            LtinF + (((size_t)kstep * 4 + fn) * 64 + lane) * 8);
      #pragma unroll
      for (int rb = 0; rb < 4; rb++) {
        unsigned int bb = (ad[rb] >> (8 * t)) & 0xffu;
        u32x4 uu;
        uu.x = ((bb & 1u)   ? 0x3F80u : 0u) | ((bb & 2u)   ? 0x3F800000u : 0u);
        uu.y = ((bb & 4u)   ? 0x3F80u : 0u) | ((bb & 8u)   ? 0x3F800000u : 0u);
        uu.z = ((bb & 16u)  ? 0x3F80u : 0u) | ((bb & 32u)  ? 0x3F800000u : 0u);
        uu.w = ((bb & 64u)  ? 0x3F80u : 0u) | ((bb & 128u) ? 0x3F800000u : 0u);
        bf16x8 a = __builtin_bit_cast(bf16x8, uu);
        #pragma unroll
        for (int fn = 0; fn < 4; fn++)
          acc[rb][fn] = __builtin_amdgcn_mfma_f32_16x16x32_bf16(a, b[fn], acc[rb][fn], 0, 0, 0);
      }
    }
  }
  // 2-pass wk-reduce through LDS -> Cpart[ks]
  float* cp = Cpart + (size_t)ks * (NTOT * NCLS);
  #pragma unroll
  for (int p = 0; p < 2; p++) {
    #pragma unroll
    for (int rbl = 0; rbl < 2; rbl++) {
      int rb = p * 2 + rbl;
      #pragma unroll
      for (int fn = 0; fn < 4; fn++)
        #pragma unroll
        for (int r4 = 0; r4 < 4; r4++)
          RED(wk, wr * 32 + rbl * 16 + lg * 4 + r4, fn * 16 + l15) = acc[rb][fn][r4];
    }
    __syncthreads();
    #pragma unroll
    for (int e = 0; e < 8; e++) {
      int idx = e * 512 + (int)threadIdx.x;  // 0..4095
      int rr = idx >> 6, c = idx & 63;
      float s = RED(0, rr, c) + RED(1, rr, c) + RED(2, rr, c) + RED(3, rr, c);
      int grow = rg * 128 + (rr >> 5) * 64 + p * 32 + (rr & 31);
      cp[(size_t)grow * 64 + c] = s;
    }
    __syncthreads();
  }
  // last-block-per-rowgroup fused epilogue
  int* sflag = (int*)&red[0][0][0];
  if (threadIdx.x == 0) {
    __threadfence();
    *sflag = atomicAdd(&cnt[rg], 1);
  }
  __syncthreads();
  if (*sflag == PKS - 1) {
    __threadfence();
    for (int e = threadIdx.x; e < 128 * 64; e += 512) {
      int il = e >> 6, c = e & 63;
      int i = rg * 128 + il;
      size_t idx = (size_t)i * NCLS + c;
      float s = 0.f;
      #pragma unroll
      for (int k = 0; k < PKS; k++) s += Cpart[(size_t)k * NTOT * NCLS + idx];
      float v = 0.5f * labels[idx] + 0.5f * (s * rdeg[i]);
      labels[idx] = v;
      LtoutF[lfrag(i, c)] = f2bf(v);
      if (last && i >= NSUP) outq[idx - (size_t)NSUP * NCLS] = v;
    }
  }
}

extern "C" void kernel_launch(void* const* d_in, const int* in_sizes, int n_in,
                              void* d_out, int out_size, void* d_ws, size_t ws_size,
                              hipStream_t stream) {
  const float* support = (const float*)d_in[0];
  const float* query   = (const float*)d_in[1];
  const float* W       = (const float*)d_in[2];
  const int*   slab    = (const int*)d_in[3];
  float* out = (float*)d_out;
  char* ws = (char*)d_ws;
  const size_t MB = (size_t)1 << 20;
  // Aliases: Apk reuses XhF (dead after emb_mfma); Cpart reuses XlF (dead after emb_mfma).
  unsigned short* XhF    = (unsigned short*)(ws);            // 8 MB
  unsigned int*   Apk    = (unsigned int*)(ws);              // 8 MB (alias)
  unsigned short* XlF    = (unsigned short*)(ws + 8 * MB);   // 8 MB
  float*          Cpart  = (float*)(ws + 8 * MB);            // 16 MB (alias, spans 8-24 MB)
  unsigned short* ehiF   = (unsigned short*)(ws + 24 * MB);  // 4 MB
  unsigned short* eloF   = (unsigned short*)(ws + 28 * MB);  // 4 MB
  unsigned short* WhF    = (unsigned short*)(ws + 32 * MB);  // 256 KB
  unsigned short* WlF    = (unsigned short*)(ws + 32 * MB + 256 * 1024); // 256 KB
  float*          labels = (float*)(ws + 33 * MB);           // 2 MB fp32 [8192][64]
  unsigned short* Lt0    = (unsigned short*)(ws + 35 * MB);  // 1 MB frag-major
  unsigned short* Lt1    = (unsigned short*)(ws + 36 * MB);  // 1 MB
  float*          rdeg   = (float*)(ws + 37 * MB);           // 32 KB
  int*            cnt    = (int*)(ws + 37 * MB + 64 * 1024); // 2.5 KB (10 iters x 64)

  splitX<<<NTOT / 4, 256, 0, stream>>>(support, query, XhF, XlF);
  splitW<<<DIN * DEMB / 8 / 256, 256, 0, stream>>>(W, WhF, WlF);
  emb_mfma<<<NTOT / 32, 256, 0, stream>>>(XhF, XlF, WhF, WlF, ehiF, eloF);
  sim_kernel<<<2080, 256, 0, stream>>>(ehiF, eloF, Apk);
  degree_kernel<<<NTOT / 16, 256, 0, stream>>>(Apk, rdeg);
  init_labels<<<NTOT * NCLS / 256, 256, 0, stream>>>(slab, labels, Lt0, cnt);
  for (int t = 0; t < 10; t++) {
    unsigned short* Li = (t & 1) ? Lt1 : Lt0;
    unsigned short* Lo = (t & 1) ? Lt0 : Lt1;
    prop_kernel<<<dim3(PKS, 64), 512, 0, stream>>>(Apk, Li, rdeg, labels, Lo, out,
                                                   Cpart, cnt + t * 64, (t == 9) ? 1 : 0);
  }
}

// Round 9
// 441.440 us; speedup vs baseline: 2.9380x; 2.9380x over previous
//
#include <hip/hip_runtime.h>

#define NSUP 4096
#define NTOT 8192
#define DIN  512
#define DEMB 256
#define NCLS 64
#define PKS  8      // prop K-splits

typedef __attribute__((ext_vector_type(8))) short bf16x8;
typedef __attribute__((ext_vector_type(4))) float f32x4;
typedef __attribute__((ext_vector_type(4))) unsigned int u32x4;

__device__ inline unsigned short f2bf(float x) {
  unsigned int u = __builtin_bit_cast(unsigned int, x);
  u += 0x7FFFu + ((u >> 16) & 1u);   // RNE
  return (unsigned short)(u >> 16);
}
__device__ inline float bf2f(unsigned short h) {
  unsigned int u = ((unsigned int)h) << 16;
  return __builtin_bit_cast(float, u);
}

// fragment-major layouts:
// e[Hi/Lo]F: [row>>4][col>>5][(row&15)+16*((col>>3)&3)][col&7]
// LtF:       [i>>5][c>>4][(c&15)+16*((i>>3)&3)][i&7]
__device__ inline size_t lfrag(int i, int c) {
  return (((size_t)(i >> 5) * (NCLS / 16) + (c >> 4)) * 64 +
          (c & 15) + 16 * ((i >> 3) & 3)) * 8 + (i & 7);
}

// ---------- 1a) split X (fp32 -> bf16 hi/lo) into fragment-major [8192][512] ----------
__global__ __launch_bounds__(256) void splitX(
    const float* __restrict__ support, const float* __restrict__ query,
    unsigned short* __restrict__ XhF, unsigned short* __restrict__ XlF) {
  int w = threadIdx.x >> 6, lane = threadIdx.x & 63;
  int row = blockIdx.x * 4 + w;
  const float* X = (row < NSUP) ? (support + (size_t)row * DIN)
                                : (query + (size_t)(row - NSUP) * DIN);
  const float4* p = (const float4*)(X + lane * 8);
  float4 a = p[0], b = p[1];
  float v[8] = {a.x, a.y, a.z, a.w, b.x, b.y, b.z, b.w};
  bf16x8 hv, lv;
  #pragma unroll
  for (int j = 0; j < 8; j++) {
    unsigned short h = f2bf(v[j]);
    hv[j] = (short)h;
    lv[j] = (short)f2bf(v[j] - bf2f(h));
  }
  size_t off = (((size_t)(row >> 4) * (DIN / 32) + (lane >> 2)) * 64 +
                (row & 15) + 16 * (lane & 3)) * 8;
  *reinterpret_cast<bf16x8*>(XhF + off) = hv;
  *reinterpret_cast<bf16x8*>(XlF + off) = lv;
}

// ---------- 1b) split W [512][256] into B-side fragment-major ----------
__global__ __launch_bounds__(256) void splitW(
    const float* __restrict__ W, unsigned short* __restrict__ WhF,
    unsigned short* __restrict__ WlF) {
  int idx = blockIdx.x * 256 + threadIdx.x;
  int n = idx & 255, kb8 = idx >> 8;       // kb8 = k-octet 0..63
  bf16x8 hv, lv;
  #pragma unroll
  for (int j = 0; j < 8; j++) {
    float v = W[(size_t)(kb8 * 8 + j) * DEMB + n];
    unsigned short h = f2bf(v);
    hv[j] = (short)h;
    lv[j] = (short)f2bf(v - bf2f(h));
  }
  size_t off = (((size_t)(n >> 4) * (DIN / 32) + (kb8 >> 2)) * 64 +
                (n & 15) + 16 * (kb8 & 3)) * 8;
  *reinterpret_cast<bf16x8*>(WhF + off) = hv;
  *reinterpret_cast<bf16x8*>(WlF + off) = lv;
}

// ---------- 1c) emb = X @ W via 4-product split-bf16 MFMA -> ehiF/eloF frag-major ----------
__global__ __launch_bounds__(256) void emb_mfma(
    const unsigned short* __restrict__ XhF, const unsigned short* __restrict__ XlF,
    const unsigned short* __restrict__ WhF, const unsigned short* __restrict__ WlF,
    unsigned short* __restrict__ ehiF, unsigned short* __restrict__ eloF) {
  __shared__ float lds[4][16][65];
  int lane = threadIdx.x & 63, w = threadIdx.x >> 6;
  int l15 = lane & 15, lg = lane >> 4;
  int rowblk0 = blockIdx.x * 2;            // 32 rows per block
  f32x4 acc[2][4] = {};
  for (int kb = 0; kb < DIN / 32; kb++) {
    bf16x8 ah[2], al[2], bh[4], bl[4];
    #pragma unroll
    for (int fm = 0; fm < 2; fm++) {
      size_t o = (((size_t)(rowblk0 + fm) * (DIN / 32) + kb) * 64 + lane) * 8;
      ah[fm] = *reinterpret_cast<const bf16x8*>(XhF + o);
      al[fm] = *reinterpret_cast<const bf16x8*>(XlF + o);
    }
    #pragma unroll
    for (int fn = 0; fn < 4; fn++) {
      size_t o = (((size_t)(w * 4 + fn) * (DIN / 32) + kb) * 64 + lane) * 8;
      bh[fn] = *reinterpret_cast<const bf16x8*>(WhF + o);
      bl[fn] = *reinterpret_cast<const bf16x8*>(WlF + o);
    }
    #pragma unroll
    for (int fm = 0; fm < 2; fm++)
      #pragma unroll
      for (int fn = 0; fn < 4; fn++) {
        acc[fm][fn] = __builtin_amdgcn_mfma_f32_16x16x32_bf16(ah[fm], bh[fn], acc[fm][fn], 0, 0, 0);
        acc[fm][fn] = __builtin_amdgcn_mfma_f32_16x16x32_bf16(ah[fm], bl[fn], acc[fm][fn], 0, 0, 0);
        acc[fm][fn] = __builtin_amdgcn_mfma_f32_16x16x32_bf16(al[fm], bh[fn], acc[fm][fn], 0, 0, 0);
        acc[fm][fn] = __builtin_amdgcn_mfma_f32_16x16x32_bf16(al[fm], bl[fn], acc[fm][fn], 0, 0, 0);
      }
  }
  // C/D (col=l15,row=lg*4+r) -> fragment-major via LDS permute
  for (int fm = 0; fm < 2; fm++) {
    #pragma unroll
    for (int fn = 0; fn < 4; fn++)
      #pragma unroll
      for (int r = 0; r < 4; r++)
        lds[w][lg * 4 + r][fn * 16 + l15] = acc[fm][fn][r];
    __syncthreads();
    #pragma unroll
    for (int cb = 0; cb < 2; cb++) {
      const float* src = &lds[w][l15][cb * 32 + lg * 8];
      bf16x8 hv, lv;
      #pragma unroll
      for (int j = 0; j < 8; j++) {
        float v = src[j];
        unsigned short h = f2bf(v);
        hv[j] = (short)h;
        lv[j] = (short)f2bf(v - bf2f(h));
      }
      size_t off = (((size_t)(rowblk0 + fm) * (DEMB / 32) + w * 2 + cb) * 64 + lane) * 8;
      *reinterpret_cast<bf16x8*>(ehiF + off) = hv;
      *reinterpret_cast<bf16x8*>(eloF + off) = lv;
    }
    __syncthreads();
  }
}

// ---------- 2) similarity: tri-linearized grid + XCD swizzle -> Apk both triangles ----------
__global__ __launch_bounds__(256) void sim_kernel(
    const unsigned short* __restrict__ ehiF, const unsigned short* __restrict__ eloF,
    unsigned int* __restrict__ Apk) {
  // 2080 upper-tri tiles; bijective XCD swizzle (2080 = 8*260), then inverse-triangular
  int bid = (blockIdx.x & 7) * 260 + (blockIdx.x >> 3);
  int r = 2079 - bid;
  int j = (int)((sqrtf((float)(8 * r + 1)) - 1.0f) * 0.5f);
  while ((j + 1) * (j + 2) / 2 <= r) ++j;
  while (j * (j + 1) / 2 > r) --j;
  int by = 63 - j;
  int bx = 63 - (r - j * (j + 1) / 2);

  __shared__ unsigned short LTn[128][8];     // normal bit-rows (ushort per 16 cols)
  __shared__ unsigned short LTt[128][8];     // transposed
  int lane = threadIdx.x & 63;
  int w = threadIdx.x >> 6, wm = w >> 1, wn = w & 1;
  int l15 = lane & 15, lg = lane >> 4;
  int arb = by * 8 + wm * 4, brb = bx * 8 + wn * 4;

  f32x4 acc[4][4] = {};
  for (int kb = 0; kb < DEMB / 32; kb++) {
    bf16x8 bh[4], bl[4];
    #pragma unroll
    for (int fn = 0; fn < 4; fn++) {
      size_t o = (((size_t)(brb + fn) * (DEMB / 32) + kb) * 64 + lane) * 8;
      bh[fn] = *reinterpret_cast<const bf16x8*>(ehiF + o);
      bl[fn] = *reinterpret_cast<const bf16x8*>(eloF + o);
    }
    #pragma unroll
    for (int fm = 0; fm < 4; fm++) {
      size_t o = (((size_t)(arb + fm) * (DEMB / 32) + kb) * 64 + lane) * 8;
      bf16x8 ah = *reinterpret_cast<const bf16x8*>(ehiF + o);
      bf16x8 al = *reinterpret_cast<const bf16x8*>(eloF + o);
      #pragma unroll
      for (int fn = 0; fn < 4; fn++) {
        acc[fm][fn] = __builtin_amdgcn_mfma_f32_16x16x32_bf16(ah, bh[fn], acc[fm][fn], 0, 0, 0);
        acc[fm][fn] = __builtin_amdgcn_mfma_f32_16x16x32_bf16(ah, bl[fn], acc[fm][fn], 0, 0, 0);
        acc[fm][fn] = __builtin_amdgcn_mfma_f32_16x16x32_bf16(al, bh[fn], acc[fm][fn], 0, 0, 0);
      }
    }
  }
  // threshold + ballot; build normal and transposed bit-rows in LDS
  #pragma unroll
  for (int fm = 0; fm < 4; fm++)
    #pragma unroll
    for (int fn = 0; fn < 4; fn++) {
      unsigned long long bal[4];
      #pragma unroll
      for (int r4 = 0; r4 < 4; r4++) {
        bal[r4] = __ballot(acc[fm][fn][r4] > 0.5f);
        if (l15 == 0)
          LTn[wm * 64 + fm * 16 + lg * 4 + r4][wn * 4 + fn] =
              (unsigned short)(bal[r4] >> (lg * 16));
      }
      unsigned int tv = 0;
      #pragma unroll
      for (int p = 0; p < 16; p++) {
        unsigned int half = (unsigned int)(bal[p & 3] >> ((p >> 2) * 16));
        tv |= ((half >> l15) & 1u) << p;
      }
      if (lg == 0) LTt[wn * 64 + fn * 16 + l15][wm * 4 + fm] = (unsigned short)tv;
    }
  __syncthreads();
  // assemble Apk dwords: dword(rowblk,S4,lane={row&15,lg}) byte t = bits k=S4*128+t*32+lg*8
  #pragma unroll
  for (int pass = 0; pass < 2; pass++) {
    int idx = pass * 256 + threadIdx.x;      // 0..511
    int rb4 = idx >> 6, ln = idx & 63;
    int lr = rb4 * 16 + (ln & 15), Lg = ln >> 4;
    unsigned int d = 0, d2 = 0;
    #pragma unroll
    for (int t = 0; t < 4; t++) {
      int bix = t * 4 + Lg;
      unsigned int u = LTn[lr][bix >> 1];
      d |= ((u >> ((bix & 1) * 8)) & 0xffu) << (t * 8);
      unsigned int u2 = LTt[lr][bix >> 1];
      d2 |= ((u2 >> ((bix & 1) * 8)) & 0xffu) << (t * 8);
    }
    Apk[((size_t)(by * 8 + rb4) * 64 + bx) * 64 + ln] = d;
    Apk[((size_t)(bx * 8 + rb4) * 64 + by) * 64 + ln] = d2;
  }
}

// ---------- 3) rdeg = 1/popcount, straight from Apk (coalesced) ----------
__global__ __launch_bounds__(256) void degree_kernel(
    const unsigned int* __restrict__ Apk, float* __restrict__ rdeg) {
  __shared__ int dg[4][16];
  int rowblk = blockIdx.x;
  int w = threadIdx.x >> 6, lane = threadIdx.x & 63;
  const unsigned int* base = Apk + (size_t)rowblk * 4096;
  int cnt = 0;
  #pragma unroll
  for (int s = 0; s < 16; s++) cnt += __popc(base[(w * 16 + s) * 64 + lane]);
  cnt += __shfl_xor(cnt, 16);
  cnt += __shfl_xor(cnt, 32);
  if (lane < 16) dg[w][lane] = cnt;
  __syncthreads();
  if (threadIdx.x < 16) {
    int c = dg[0][threadIdx.x] + dg[1][threadIdx.x] + dg[2][threadIdx.x] + dg[3][threadIdx.x];
    rdeg[rowblk * 16 + threadIdx.x] = (c == 0) ? 1.f : 1.f / (float)c;
  }
}

// ---------- 4) label init: support one-hot, query zero ----------
__global__ __launch_bounds__(256) void init_labels(
    const int* __restrict__ slab, float* __restrict__ labels,
    unsigned short* __restrict__ LtF) {
  int idx = blockIdx.x * 256 + threadIdx.x;
  int i = idx >> 6, c = idx & 63;
  float v = 0.f;
  if (i < NSUP && slab[i] == c) v = 1.f;
  labels[idx] = v;
  LtF[lfrag(i, c)] = f2bf(v);
}

// ---------- 5a) prop GEMM: M-register-blocked K-split, Cpart[ks] = A[:,chunk]@L[chunk] ----------
// grid dim3(PKS, 64): ks = blockIdx.x (XCD-resident LtF chunk), rg = blockIdx.y (128 rows)
// block 512 thr = 8 waves (wr 2 x wk 4); wave = 4 rowblks (64 rows) x 256 K
#define RED(k, row, col) red[k][row][(col) ^ ((((row) >> 2) & 3) << 4)]
__global__ __launch_bounds__(512, 4) void prop_gemm(
    const unsigned int* __restrict__ Apk, const unsigned short* __restrict__ LtinF,
    float* __restrict__ Cpart) {
  __shared__ float red[4][64][64];          // 64 KB, col-swizzled
  int lane = threadIdx.x & 63;
  int w = threadIdx.x >> 6;
  int wr = w >> 2, wk = w & 3;
  int l15 = lane & 15, lg = lane >> 4;
  int ks = blockIdx.x, rg = blockIdx.y;
  int rb0 = rg * 8 + wr * 4;                // first of 4 rowblks
  int s4base = ks * 8 + wk * 2;             // 2 S4 units (128 K each) per wave

  f32x4 acc[4][4] = {};
  #pragma unroll
  for (int s4 = 0; s4 < 2; s4++) {
    unsigned int ad[4];
    #pragma unroll
    for (int rb = 0; rb < 4; rb++)
      ad[rb] = Apk[((size_t)(rb0 + rb) * 64 + (s4base + s4)) * 64 + lane];
    #pragma unroll
    for (int t = 0; t < 4; t++) {
      int kstep = (s4base + s4) * 4 + t;
      bf16x8 b[4];
      #pragma unroll
      for (int fn = 0; fn < 4; fn++)
        b[fn] = *reinterpret_cast<const bf16x8*>(
            LtinF + (((size_t)kstep * 4 + fn) * 64 + lane) * 8);
      #pragma unroll
      for (int rb = 0; rb < 4; rb++) {
        unsigned int bb = (ad[rb] >> (8 * t)) & 0xffu;
        u32x4 uu;
        uu.x = ((bb & 1u)   ? 0x3F80u : 0u) | ((bb & 2u)   ? 0x3F800000u : 0u);
        uu.y = ((bb & 4u)   ? 0x3F80u : 0u) | ((bb & 8u)   ? 0x3F800000u : 0u);
        uu.z = ((bb & 16u)  ? 0x3F80u : 0u) | ((bb & 32u)  ? 0x3F800000u : 0u);
        uu.w = ((bb & 64u)  ? 0x3F80u : 0u) | ((bb & 128u) ? 0x3F800000u : 0u);
        bf16x8 a = __builtin_bit_cast(bf16x8, uu);
        #pragma unroll
        for (int fn = 0; fn < 4; fn++)
          acc[rb][fn] = __builtin_amdgcn_mfma_f32_16x16x32_bf16(a, b[fn], acc[rb][fn], 0, 0, 0);
      }
    }
  }
  // 2-pass wk-reduce through LDS -> Cpart[ks]
  float* cp = Cpart + (size_t)ks * (NTOT * NCLS);
  #pragma unroll
  for (int p = 0; p < 2; p++) {
    #pragma unroll
    for (int rbl = 0; rbl < 2; rbl++) {
      int rb = p * 2 + rbl;
      #pragma unroll
      for (int fn = 0; fn < 4; fn++)
        #pragma unroll
        for (int r4 = 0; r4 < 4; r4++)
          RED(wk, wr * 32 + rbl * 16 + lg * 4 + r4, fn * 16 + l15) = acc[rb][fn][r4];
    }
    __syncthreads();
    #pragma unroll
    for (int e = 0; e < 8; e++) {
      int idx = e * 512 + (int)threadIdx.x;  // 0..4095
      int rr = idx >> 6, c = idx & 63;
      float s = RED(0, rr, c) + RED(1, rr, c) + RED(2, rr, c) + RED(3, rr, c);
      int grow = rg * 128 + (rr >> 5) * 64 + p * 32 + (rr & 31);
      cp[(size_t)grow * 64 + c] = s;
    }
    __syncthreads();
  }
}

// ---------- 5b) prop epilogue: reduce K-splits, 0.5*old + 0.5*s/deg, refresh LtF ----------
__global__ __launch_bounds__(256) void prop_epi(
    const float* __restrict__ Cpart, const float* __restrict__ rdeg,
    float* __restrict__ labels, unsigned short* __restrict__ LtoutF,
    float* __restrict__ outq, int last) {
  int idx = blockIdx.x * 256 + threadIdx.x;  // 0..524287
  int i = idx >> 6, c = idx & 63;
  float s = 0.f;
  #pragma unroll
  for (int k = 0; k < PKS; k++) s += Cpart[(size_t)k * (NTOT * NCLS) + idx];
  float v = 0.5f * labels[idx] + 0.5f * (s * rdeg[i]);
  labels[idx] = v;
  LtoutF[lfrag(i, c)] = f2bf(v);
  if (last && i >= NSUP) outq[idx - NSUP * NCLS] = v;
}

extern "C" void kernel_launch(void* const* d_in, const int* in_sizes, int n_in,
                              void* d_out, int out_size, void* d_ws, size_t ws_size,
                              hipStream_t stream) {
  const float* support = (const float*)d_in[0];
  const float* query   = (const float*)d_in[1];
  const float* W       = (const float*)d_in[2];
  const int*   slab    = (const int*)d_in[3];
  float* out = (float*)d_out;
  char* ws = (char*)d_ws;
  const size_t MB = (size_t)1 << 20;
  // Aliases: Apk reuses XhF (dead after emb_mfma); Cpart reuses XlF (dead after emb_mfma).
  unsigned short* XhF    = (unsigned short*)(ws);            // 8 MB
  unsigned int*   Apk    = (unsigned int*)(ws);              // 8 MB (alias)
  unsigned short* XlF    = (unsigned short*)(ws + 8 * MB);   // 8 MB
  float*          Cpart  = (float*)(ws + 8 * MB);            // 16 MB (alias, spans 8-24 MB)
  unsigned short* ehiF   = (unsigned short*)(ws + 24 * MB);  // 4 MB
  unsigned short* eloF   = (unsigned short*)(ws + 28 * MB);  // 4 MB
  unsigned short* WhF    = (unsigned short*)(ws + 32 * MB);  // 256 KB
  unsigned short* WlF    = (unsigned short*)(ws + 32 * MB + 256 * 1024); // 256 KB
  float*          labels = (float*)(ws + 33 * MB);           // 2 MB fp32 [8192][64]
  unsigned short* Lt0    = (unsigned short*)(ws + 35 * MB);  // 1 MB frag-major
  unsigned short* Lt1    = (unsigned short*)(ws + 36 * MB);  // 1 MB
  float*          rdeg   = (float*)(ws + 37 * MB);           // 32 KB

  splitX<<<NTOT / 4, 256, 0, stream>>>(support, query, XhF, XlF);
  splitW<<<DIN * DEMB / 8 / 256, 256, 0, stream>>>(W, WhF, WlF);
  emb_mfma<<<NTOT / 32, 256, 0, stream>>>(XhF, XlF, WhF, WlF, ehiF, eloF);
  sim_kernel<<<2080, 256, 0, stream>>>(ehiF, eloF, Apk);
  degree_kernel<<<NTOT / 16, 256, 0, stream>>>(Apk, rdeg);
  init_labels<<<NTOT * NCLS / 256, 256, 0, stream>>>(slab, labels, Lt0);
  for (int t = 0; t < 10; t++) {
    unsigned short* Li = (t & 1) ? Lt1 : Lt0;
    unsigned short* Lo = (t & 1) ? Lt0 : Lt1;
    prop_gemm<<<dim3(PKS, 64), 512, 0, stream>>>(Apk, Li, Cpart);
    prop_epi<<<NTOT * NCLS / 256, 256, 0, stream>>>(Cpart, rdeg, labels, Lo, out, (t == 9) ? 1 : 0);
  }
}

// Round 10
// 380.265 us; speedup vs baseline: 3.4106x; 1.1609x over previous
//
#include <hip/hip_runtime.h>

#define NSUP 4096
#define NTOT 8192
#define DIN  512
#define DEMB 256
#define NCLS 64
#define PKS  8      // prop K-splits

typedef __attribute__((ext_vector_type(8))) short bf16x8;
typedef __attribute__((ext_vector_type(4))) float f32x4;
typedef __attribute__((ext_vector_type(4))) unsigned int u32x4;

__device__ inline unsigned short f2bf(float x) {
  unsigned int u = __builtin_bit_cast(unsigned int, x);
  u += 0x7FFFu + ((u >> 16) & 1u);   // RNE
  return (unsigned short)(u >> 16);
}
__device__ inline float bf2f(unsigned short h) {
  unsigned int u = ((unsigned int)h) << 16;
  return __builtin_bit_cast(float, u);
}

// fragment-major layouts:
// e[Hi/Lo]F: [row>>4][col>>5][(row&15)+16*((col>>3)&3)][col&7]
// LtF:       [i>>5][c>>4][(c&15)+16*((i>>3)&3)][i&7]
__device__ inline size_t lfrag(int i, int c) {
  return (((size_t)(i >> 5) * (NCLS / 16) + (c >> 4)) * 64 +
          (c & 15) + 16 * ((i >> 3) & 3)) * 8 + (i & 7);
}

// ---------- 1a) split X (fp32 -> bf16 hi/lo) into fragment-major [8192][512] ----------
__global__ __launch_bounds__(256) void splitX(
    const float* __restrict__ support, const float* __restrict__ query,
    unsigned short* __restrict__ XhF, unsigned short* __restrict__ XlF) {
  int w = threadIdx.x >> 6, lane = threadIdx.x & 63;
  int row = blockIdx.x * 4 + w;
  const float* X = (row < NSUP) ? (support + (size_t)row * DIN)
                                : (query + (size_t)(row - NSUP) * DIN);
  const float4* p = (const float4*)(X + lane * 8);
  float4 a = p[0], b = p[1];
  float v[8] = {a.x, a.y, a.z, a.w, b.x, b.y, b.z, b.w};
  bf16x8 hv, lv;
  #pragma unroll
  for (int j = 0; j < 8; j++) {
    unsigned short h = f2bf(v[j]);
    hv[j] = (short)h;
    lv[j] = (short)f2bf(v[j] - bf2f(h));
  }
  size_t off = (((size_t)(row >> 4) * (DIN / 32) + (lane >> 2)) * 64 +
                (row & 15) + 16 * (lane & 3)) * 8;
  *reinterpret_cast<bf16x8*>(XhF + off) = hv;
  *reinterpret_cast<bf16x8*>(XlF + off) = lv;
}

// ---------- 1b) split W [512][256] into B-side fragment-major ----------
__global__ __launch_bounds__(256) void splitW(
    const float* __restrict__ W, unsigned short* __restrict__ WhF,
    unsigned short* __restrict__ WlF) {
  int idx = blockIdx.x * 256 + threadIdx.x;
  int n = idx & 255, kb8 = idx >> 8;       // kb8 = k-octet 0..63
  bf16x8 hv, lv;
  #pragma unroll
  for (int j = 0; j < 8; j++) {
    float v = W[(size_t)(kb8 * 8 + j) * DEMB + n];
    unsigned short h = f2bf(v);
    hv[j] = (short)h;
    lv[j] = (short)f2bf(v - bf2f(h));
  }
  size_t off = (((size_t)(n >> 4) * (DIN / 32) + (kb8 >> 2)) * 64 +
                (n & 15) + 16 * (kb8 & 3)) * 8;
  *reinterpret_cast<bf16x8*>(WhF + off) = hv;
  *reinterpret_cast<bf16x8*>(WlF + off) = lv;
}

// ---------- 1c) emb = X @ W via 4-product split-bf16 MFMA -> ehiF/eloF frag-major ----------
__global__ __launch_bounds__(256) void emb_mfma(
    const unsigned short* __restrict__ XhF, const unsigned short* __restrict__ XlF,
    const unsigned short* __restrict__ WhF, const unsigned short* __restrict__ WlF,
    unsigned short* __restrict__ ehiF, unsigned short* __restrict__ eloF) {
  __shared__ float lds[4][16][65];
  int lane = threadIdx.x & 63, w = threadIdx.x >> 6;
  int l15 = lane & 15, lg = lane >> 4;
  int rowblk0 = blockIdx.x * 2;            // 32 rows per block
  f32x4 acc[2][4] = {};
  for (int kb = 0; kb < DIN / 32; kb++) {
    bf16x8 ah[2], al[2], bh[4], bl[4];
    #pragma unroll
    for (int fm = 0; fm < 2; fm++) {
      size_t o = (((size_t)(rowblk0 + fm) * (DIN / 32) + kb) * 64 + lane) * 8;
      ah[fm] = *reinterpret_cast<const bf16x8*>(XhF + o);
      al[fm] = *reinterpret_cast<const bf16x8*>(XlF + o);
    }
    #pragma unroll
    for (int fn = 0; fn < 4; fn++) {
      size_t o = (((size_t)(w * 4 + fn) * (DIN / 32) + kb) * 64 + lane) * 8;
      bh[fn] = *reinterpret_cast<const bf16x8*>(WhF + o);
      bl[fn] = *reinterpret_cast<const bf16x8*>(WlF + o);
    }
    #pragma unroll
    for (int fm = 0; fm < 2; fm++)
      #pragma unroll
      for (int fn = 0; fn < 4; fn++) {
        acc[fm][fn] = __builtin_amdgcn_mfma_f32_16x16x32_bf16(ah[fm], bh[fn], acc[fm][fn], 0, 0, 0);
        acc[fm][fn] = __builtin_amdgcn_mfma_f32_16x16x32_bf16(ah[fm], bl[fn], acc[fm][fn], 0, 0, 0);
        acc[fm][fn] = __builtin_amdgcn_mfma_f32_16x16x32_bf16(al[fm], bh[fn], acc[fm][fn], 0, 0, 0);
        acc[fm][fn] = __builtin_amdgcn_mfma_f32_16x16x32_bf16(al[fm], bl[fn], acc[fm][fn], 0, 0, 0);
      }
  }
  // C/D (col=l15,row=lg*4+r) -> fragment-major via LDS permute
  for (int fm = 0; fm < 2; fm++) {
    #pragma unroll
    for (int fn = 0; fn < 4; fn++)
      #pragma unroll
      for (int r = 0; r < 4; r++)
        lds[w][lg * 4 + r][fn * 16 + l15] = acc[fm][fn][r];
    __syncthreads();
    #pragma unroll
    for (int cb = 0; cb < 2; cb++) {
      const float* src = &lds[w][l15][cb * 32 + lg * 8];
      bf16x8 hv, lv;
      #pragma unroll
      for (int j = 0; j < 8; j++) {
        float v = src[j];
        unsigned short h = f2bf(v);
        hv[j] = (short)h;
        lv[j] = (short)f2bf(v - bf2f(h));
      }
      size_t off = (((size_t)(rowblk0 + fm) * (DEMB / 32) + w * 2 + cb) * 64 + lane) * 8;
      *reinterpret_cast<bf16x8*>(ehiF + off) = hv;
      *reinterpret_cast<bf16x8*>(eloF + off) = lv;
    }
    __syncthreads();
  }
}

// ---------- 2) similarity: tri-linearized grid + XCD swizzle -> Apk both triangles ----------
__global__ __launch_bounds__(256) void sim_kernel(
    const unsigned short* __restrict__ ehiF, const unsigned short* __restrict__ eloF,
    unsigned int* __restrict__ Apk) {
  // 2080 upper-tri tiles; bijective XCD swizzle (2080 = 8*260), then inverse-triangular
  int bid = (blockIdx.x & 7) * 260 + (blockIdx.x >> 3);
  int r = 2079 - bid;
  int j = (int)((sqrtf((float)(8 * r + 1)) - 1.0f) * 0.5f);
  while ((j + 1) * (j + 2) / 2 <= r) ++j;
  while (j * (j + 1) / 2 > r) --j;
  int by = 63 - j;
  int bx = 63 - (r - j * (j + 1) / 2);

  __shared__ unsigned short LTn[128][8];     // normal bit-rows (ushort per 16 cols)
  __shared__ unsigned short LTt[128][8];     // transposed
  int lane = threadIdx.x & 63;
  int w = threadIdx.x >> 6, wm = w >> 1, wn = w & 1;
  int l15 = lane & 15, lg = lane >> 4;
  int arb = by * 8 + wm * 4, brb = bx * 8 + wn * 4;

  f32x4 acc[4][4] = {};
  #pragma unroll 2
  for (int kb = 0; kb < DEMB / 32; kb++) {
    bf16x8 bh[4], bl[4];
    #pragma unroll
    for (int fn = 0; fn < 4; fn++) {
      size_t o = (((size_t)(brb + fn) * (DEMB / 32) + kb) * 64 + lane) * 8;
      bh[fn] = *reinterpret_cast<const bf16x8*>(ehiF + o);
      bl[fn] = *reinterpret_cast<const bf16x8*>(eloF + o);
    }
    #pragma unroll
    for (int fm = 0; fm < 4; fm++) {
      size_t o = (((size_t)(arb + fm) * (DEMB / 32) + kb) * 64 + lane) * 8;
      bf16x8 ah = *reinterpret_cast<const bf16x8*>(ehiF + o);
      bf16x8 al = *reinterpret_cast<const bf16x8*>(eloF + o);
      #pragma unroll
      for (int fn = 0; fn < 4; fn++) {
        acc[fm][fn] = __builtin_amdgcn_mfma_f32_16x16x32_bf16(ah, bh[fn], acc[fm][fn], 0, 0, 0);
        acc[fm][fn] = __builtin_amdgcn_mfma_f32_16x16x32_bf16(ah, bl[fn], acc[fm][fn], 0, 0, 0);
        acc[fm][fn] = __builtin_amdgcn_mfma_f32_16x16x32_bf16(al, bh[fn], acc[fm][fn], 0, 0, 0);
      }
    }
  }
  // threshold + ballot -> LTn only (transpose moved to LDS, R4-verified pattern)
  #pragma unroll
  for (int fm = 0; fm < 4; fm++)
    #pragma unroll
    for (int fn = 0; fn < 4; fn++)
      #pragma unroll
      for (int r4 = 0; r4 < 4; r4++) {
        unsigned long long bal = __ballot(acc[fm][fn][r4] > 0.5f);
        if (l15 == 0)
          LTn[wm * 64 + fm * 16 + lg * 4 + r4][wn * 4 + fn] =
              (unsigned short)(bal >> (lg * 16));
      }
  __syncthreads();
  // 16x16 bit-transpose LTn -> LTt, one tile per thread (64 tiles)
  if (threadIdx.x < 64) {
    int tr = threadIdx.x >> 3, tc = threadIdx.x & 7;
    unsigned int m[16], t;
    #pragma unroll
    for (int q = 0; q < 16; q++) m[q] = LTn[tr * 16 + q][tc];
    #pragma unroll
    for (int i = 0; i < 8; i++) { t = ((m[i] >> 8) ^ m[i + 8]) & 0x00FFu; m[i + 8] ^= t; m[i] ^= t << 8; }
    #pragma unroll
    for (int g = 0; g < 16; g += 8)
      #pragma unroll
      for (int i = g; i < g + 4; i++) { t = ((m[i] >> 4) ^ m[i + 4]) & 0x0F0Fu; m[i + 4] ^= t; m[i] ^= t << 4; }
    #pragma unroll
    for (int g = 0; g < 16; g += 4)
      #pragma unroll
      for (int i = g; i < g + 2; i++) { t = ((m[i] >> 2) ^ m[i + 2]) & 0x3333u; m[i + 2] ^= t; m[i] ^= t << 2; }
    #pragma unroll
    for (int g = 0; g < 16; g += 2) { t = ((m[g] >> 1) ^ m[g + 1]) & 0x5555u; m[g + 1] ^= t; m[g] ^= t << 1; }
    #pragma unroll
    for (int q = 0; q < 16; q++) LTt[tc * 16 + q][tr] = (unsigned short)m[q];
  }
  __syncthreads();
  // assemble Apk dwords: dword(rowblk,S4,lane={row&15,lg}) byte t = bits k=S4*128+t*32+lg*8
  #pragma unroll
  for (int pass = 0; pass < 2; pass++) {
    int idx = pass * 256 + threadIdx.x;      // 0..511
    int rb4 = idx >> 6, ln = idx & 63;
    int lr = rb4 * 16 + (ln & 15), Lg = ln >> 4;
    unsigned int d = 0, d2 = 0;
    #pragma unroll
    for (int t = 0; t < 4; t++) {
      int bix = t * 4 + Lg;
      unsigned int u = LTn[lr][bix >> 1];
      d |= ((u >> ((bix & 1) * 8)) & 0xffu) << (t * 8);
      unsigned int u2 = LTt[lr][bix >> 1];
      d2 |= ((u2 >> ((bix & 1) * 8)) & 0xffu) << (t * 8);
    }
    Apk[((size_t)(by * 8 + rb4) * 64 + bx) * 64 + ln] = d;
    Apk[((size_t)(bx * 8 + rb4) * 64 + by) * 64 + ln] = d2;
  }
}

// ---------- 3) rdeg = 1/popcount, straight from Apk (coalesced) ----------
__global__ __launch_bounds__(256) void degree_kernel(
    const unsigned int* __restrict__ Apk, float* __restrict__ rdeg) {
  __shared__ int dg[4][16];
  int rowblk = blockIdx.x;
  int w = threadIdx.x >> 6, lane = threadIdx.x & 63;
  const unsigned int* base = Apk + (size_t)rowblk * 4096;
  int cnt = 0;
  #pragma unroll
  for (int s = 0; s < 16; s++) cnt += __popc(base[(w * 16 + s) * 64 + lane]);
  cnt += __shfl_xor(cnt, 16);
  cnt += __shfl_xor(cnt, 32);
  if (lane < 16) dg[w][lane] = cnt;
  __syncthreads();
  if (threadIdx.x < 16) {
    int c = dg[0][threadIdx.x] + dg[1][threadIdx.x] + dg[2][threadIdx.x] + dg[3][threadIdx.x];
    rdeg[rowblk * 16 + threadIdx.x] = (c == 0) ? 1.f : 1.f / (float)c;
  }
}

// ---------- 4) label init: support one-hot, query zero ----------
__global__ __launch_bounds__(256) void init_labels(
    const int* __restrict__ slab, float* __restrict__ labels,
    unsigned short* __restrict__ LtF) {
  int idx = blockIdx.x * 256 + threadIdx.x;
  int i = idx >> 6, c = idx & 63;
  float v = 0.f;
  if (i < NSUP && slab[i] == c) v = 1.f;
  labels[idx] = v;
  LtF[lfrag(i, c)] = f2bf(v);
}

// ---------- 5a) prop GEMM: M-register-blocked K-split, Cpart[ks] = A[:,chunk]@L[chunk] ----------
// grid dim3(PKS, 64): ks = blockIdx.x (XCD-resident LtF chunk), rg = blockIdx.y (128 rows)
// block 512 thr = 8 waves (wr 2 x wk 4); wave = 4 rowblks (64 rows) x 256 K
#define RED(k, row, col) red[k][row][(col) ^ ((((row) >> 2) & 3) << 4)]
__global__ __launch_bounds__(512, 4) void prop_gemm(
    const unsigned int* __restrict__ Apk, const unsigned short* __restrict__ LtinF,
    float* __restrict__ Cpart) {
  __shared__ float red[4][64][64];          // 64 KB, col-swizzled
  int lane = threadIdx.x & 63;
  int w = threadIdx.x >> 6;
  int wr = w >> 2, wk = w & 3;
  int l15 = lane & 15, lg = lane >> 4;
  int ks = blockIdx.x, rg = blockIdx.y;
  int rb0 = rg * 8 + wr * 4;                // first of 4 rowblks
  int s4base = ks * 8 + wk * 2;             // 2 S4 units (128 K each) per wave

  f32x4 acc[4][4] = {};
  #pragma unroll
  for (int s4 = 0; s4 < 2; s4++) {
    unsigned int ad[4];
    #pragma unroll
    for (int rb = 0; rb < 4; rb++)
      ad[rb] = Apk[((size_t)(rb0 + rb) * 64 + (s4base + s4)) * 64 + lane];
    #pragma unroll
    for (int t = 0; t < 4; t++) {
      int kstep = (s4base + s4) * 4 + t;
      bf16x8 b[4];
      #pragma unroll
      for (int fn = 0; fn < 4; fn++)
        b[fn] = *reinterpret_cast<const bf16x8*>(
            LtinF + (((size_t)kstep * 4 + fn) * 64 + lane) * 8);
      #pragma unroll
      for (int rb = 0; rb < 4; rb++) {
        unsigned int bb = (ad[rb] >> (8 * t)) & 0xffu;
        u32x4 uu;
        uu.x = ((bb & 1u)   ? 0x3F80u : 0u) | ((bb & 2u)   ? 0x3F800000u : 0u);
        uu.y = ((bb & 4u)   ? 0x3F80u : 0u) | ((bb & 8u)   ? 0x3F800000u : 0u);
        uu.z = ((bb & 16u)  ? 0x3F80u : 0u) | ((bb & 32u)  ? 0x3F800000u : 0u);
        uu.w = ((bb & 64u)  ? 0x3F80u : 0u) | ((bb & 128u) ? 0x3F800000u : 0u);
        bf16x8 a = __builtin_bit_cast(bf16x8, uu);
        #pragma unroll
        for (int fn = 0; fn < 4; fn++)
          acc[rb][fn] = __builtin_amdgcn_mfma_f32_16x16x32_bf16(a, b[fn], acc[rb][fn], 0, 0, 0);
      }
    }
  }
  // 2-pass wk-reduce through LDS -> Cpart[ks]
  float* cp = Cpart + (size_t)ks * (NTOT * NCLS);
  #pragma unroll
  for (int p = 0; p < 2; p++) {
    #pragma unroll
    for (int rbl = 0; rbl < 2; rbl++) {
      int rb = p * 2 + rbl;
      #pragma unroll
      for (int fn = 0; fn < 4; fn++)
        #pragma unroll
        for (int r4 = 0; r4 < 4; r4++)
          RED(wk, wr * 32 + rbl * 16 + lg * 4 + r4, fn * 16 + l15) = acc[rb][fn][r4];
    }
    __syncthreads();
    #pragma unroll
    for (int e = 0; e < 8; e++) {
      int idx = e * 512 + (int)threadIdx.x;  // 0..4095
      int rr = idx >> 6, c = idx & 63;
      float s = RED(0, rr, c) + RED(1, rr, c) + RED(2, rr, c) + RED(3, rr, c);
      int grow = rg * 128 + (rr >> 5) * 64 + p * 32 + (rr & 31);
      cp[(size_t)grow * 64 + c] = s;
    }
    __syncthreads();
  }
}

// ---------- 5b) prop epilogue: vectorized K-split reduce + LDS-staged LtF write ----------
// 256 blocks x 256 thr; block = 32 rows x 64 cols; thread = 8 consecutive cols
__global__ __launch_bounds__(256) void prop_epi(
    const float* __restrict__ Cpart, const float* __restrict__ rdeg,
    float* __restrict__ labels, unsigned short* __restrict__ LtoutF,
    float* __restrict__ outq, int last) {
  __shared__ unsigned short stile[2048];     // lfrag-local 4 KB tile
  int i_loc = threadIdx.x >> 3, c0 = (threadIdx.x & 7) * 8;
  int i = blockIdx.x * 32 + i_loc;
  int idx = i * NCLS + c0;
  float4 s0 = make_float4(0.f, 0.f, 0.f, 0.f), s1 = s0;
  #pragma unroll
  for (int k = 0; k < PKS; k++) {
    const float4* cp = (const float4*)(Cpart + (size_t)k * (NTOT * NCLS) + idx);
    float4 a = cp[0], b = cp[1];
    s0.x += a.x; s0.y += a.y; s0.z += a.z; s0.w += a.w;
    s1.x += b.x; s1.y += b.y; s1.z += b.z; s1.w += b.w;
  }
  float rd = 0.5f * rdeg[i];
  const float4* lp = (const float4*)(labels + idx);
  float4 l0 = lp[0], l1 = lp[1];
  float v[8];
  v[0] = 0.5f * l0.x + s0.x * rd;  v[1] = 0.5f * l0.y + s0.y * rd;
  v[2] = 0.5f * l0.z + s0.z * rd;  v[3] = 0.5f * l0.w + s0.w * rd;
  v[4] = 0.5f * l1.x + s1.x * rd;  v[5] = 0.5f * l1.y + s1.y * rd;
  v[6] = 0.5f * l1.z + s1.z * rd;  v[7] = 0.5f * l1.w + s1.w * rd;
  float4 o0 = make_float4(v[0], v[1], v[2], v[3]);
  float4 o1 = make_float4(v[4], v[5], v[6], v[7]);
  ((float4*)(labels + idx))[0] = o0;
  ((float4*)(labels + idx))[1] = o1;
  if (last && i >= NSUP) {
    float4* oq = (float4*)(outq + idx - NSUP * NCLS);
    oq[0] = o0; oq[1] = o1;
  }
  // stage bf16 in lfrag-local order: off = (c>>4)*512 + ((c&15)+16*((i_loc>>3)&3))*8 + (i_loc&7)
  int sb = (c0 >> 4) * 512 + ((i_loc >> 3) & 3) * 128 + (i_loc & 7);
  #pragma unroll
  for (int jj = 0; jj < 8; jj++)
    stile[sb + ((c0 + jj) & 15) * 8] = f2bf(v[jj]);
  __syncthreads();
  // stream out: contiguous 4 KB run per block, 16 B per thread
  *reinterpret_cast<bf16x8*>(LtoutF + (size_t)blockIdx.x * 2048 + threadIdx.x * 8) =
      *reinterpret_cast<const bf16x8*>(&stile[threadIdx.x * 8]);
}

extern "C" void kernel_launch(void* const* d_in, const int* in_sizes, int n_in,
                              void* d_out, int out_size, void* d_ws, size_t ws_size,
                              hipStream_t stream) {
  const float* support = (const float*)d_in[0];
  const float* query   = (const float*)d_in[1];
  const float* W       = (const float*)d_in[2];
  const int*   slab    = (const int*)d_in[3];
  float* out = (float*)d_out;
  char* ws = (char*)d_ws;
  const size_t MB = (size_t)1 << 20;
  // Aliases: Apk reuses XhF (dead after emb_mfma); Cpart reuses XlF (dead after emb_mfma).
  unsigned short* XhF    = (unsigned short*)(ws);            // 8 MB
  unsigned int*   Apk    = (unsigned int*)(ws);              // 8 MB (alias)
  unsigned short* XlF    = (unsigned short*)(ws + 8 * MB);   // 8 MB
  float*          Cpart  = (float*)(ws + 8 * MB);            // 16 MB (alias, spans 8-24 MB)
  unsigned short* ehiF   = (unsigned short*)(ws + 24 * MB);  // 4 MB
  unsigned short* eloF   = (unsigned short*)(ws + 28 * MB);  // 4 MB
  unsigned short* WhF    = (unsigned short*)(ws + 32 * MB);  // 256 KB
  unsigned short* WlF    = (unsigned short*)(ws + 32 * MB + 256 * 1024); // 256 KB
  float*          labels = (float*)(ws + 33 * MB);           // 2 MB fp32 [8192][64]
  unsigned short* Lt0    = (unsigned short*)(ws + 35 * MB);  // 1 MB frag-major
  unsigned short* Lt1    = (unsigned short*)(ws + 36 * MB);  // 1 MB
  float*          rdeg   = (float*)(ws + 37 * MB);           // 32 KB

  splitX<<<NTOT / 4, 256, 0, stream>>>(support, query, XhF, XlF);
  splitW<<<DIN * DEMB / 8 / 256, 256, 0, stream>>>(W, WhF, WlF);
  emb_mfma<<<NTOT / 32, 256, 0, stream>>>(XhF, XlF, WhF, WlF, ehiF, eloF);
  sim_kernel<<<2080, 256, 0, stream>>>(ehiF, eloF, Apk);
  degree_kernel<<<NTOT / 16, 256, 0, stream>>>(Apk, rdeg);
  init_labels<<<NTOT * NCLS / 256, 256, 0, stream>>>(slab, labels, Lt0);
  for (int t = 0; t < 10; t++) {
    unsigned short* Li = (t & 1) ? Lt1 : Lt0;
    unsigned short* Lo = (t & 1) ? Lt0 : Lt1;
    prop_gemm<<<dim3(PKS, 64), 512, 0, stream>>>(Apk, Li, Cpart);
    prop_epi<<<NTOT / 32, 256, 0, stream>>>(Cpart, rdeg, labels, Lo, out, (t == 9) ? 1 : 0);
  }
}

// Round 11
// 322.230 us; speedup vs baseline: 4.0249x; 1.1801x over previous
//
#include <hip/hip_runtime.h>

#define NSUP 4096
#define NTOT 8192
#define DIN  512
#define DEMB 256
#define NCLS 64

typedef __attribute__((ext_vector_type(8))) short bf16x8;
typedef __attribute__((ext_vector_type(4))) float f32x4;
typedef __attribute__((ext_vector_type(4))) unsigned int u32x4;

__device__ inline unsigned short f2bf(float x) {
  unsigned int u = __builtin_bit_cast(unsigned int, x);
  u += 0x7FFFu + ((u >> 16) & 1u);   // RNE
  return (unsigned short)(u >> 16);
}
__device__ inline float bf2f(unsigned short h) {
  unsigned int u = ((unsigned int)h) << 16;
  return __builtin_bit_cast(float, u);
}

// fragment-major layouts:
// e[Hi/Lo]F: [row>>4][col>>5][(row&15)+16*((col>>3)&3)][col&7]
// LtF:       [i>>5][c>>4][(c&15)+16*((i>>3)&3)][i&7]
__device__ inline size_t lfrag(int i, int c) {
  return (((size_t)(i >> 5) * (NCLS / 16) + (c >> 4)) * 64 +
          (c & 15) + 16 * ((i >> 3) & 3)) * 8 + (i & 7);
}

// ---------- 1a) split X (fp32 -> bf16 hi/lo) into fragment-major [8192][512] ----------
__global__ __launch_bounds__(256) void splitX(
    const float* __restrict__ support, const float* __restrict__ query,
    unsigned short* __restrict__ XhF, unsigned short* __restrict__ XlF) {
  int w = threadIdx.x >> 6, lane = threadIdx.x & 63;
  int row = blockIdx.x * 4 + w;
  const float* X = (row < NSUP) ? (support + (size_t)row * DIN)
                                : (query + (size_t)(row - NSUP) * DIN);
  const float4* p = (const float4*)(X + lane * 8);
  float4 a = p[0], b = p[1];
  float v[8] = {a.x, a.y, a.z, a.w, b.x, b.y, b.z, b.w};
  bf16x8 hv, lv;
  #pragma unroll
  for (int j = 0; j < 8; j++) {
    unsigned short h = f2bf(v[j]);
    hv[j] = (short)h;
    lv[j] = (short)f2bf(v[j] - bf2f(h));
  }
  size_t off = (((size_t)(row >> 4) * (DIN / 32) + (lane >> 2)) * 64 +
                (row & 15) + 16 * (lane & 3)) * 8;
  *reinterpret_cast<bf16x8*>(XhF + off) = hv;
  *reinterpret_cast<bf16x8*>(XlF + off) = lv;
}

// ---------- 1b) split W [512][256] into B-side fragment-major ----------
__global__ __launch_bounds__(256) void splitW(
    const float* __restrict__ W, unsigned short* __restrict__ WhF,
    unsigned short* __restrict__ WlF) {
  int idx = blockIdx.x * 256 + threadIdx.x;
  int n = idx & 255, kb8 = idx >> 8;       // kb8 = k-octet 0..63
  bf16x8 hv, lv;
  #pragma unroll
  for (int j = 0; j < 8; j++) {
    float v = W[(size_t)(kb8 * 8 + j) * DEMB + n];
    unsigned short h = f2bf(v);
    hv[j] = (short)h;
    lv[j] = (short)f2bf(v - bf2f(h));
  }
  size_t off = (((size_t)(n >> 4) * (DIN / 32) + (kb8 >> 2)) * 64 +
                (n & 15) + 16 * (kb8 & 3)) * 8;
  *reinterpret_cast<bf16x8*>(WhF + off) = hv;
  *reinterpret_cast<bf16x8*>(WlF + off) = lv;
}

// ---------- 1c) emb = X @ W via 4-product split-bf16 MFMA -> ehiF/eloF frag-major ----------
__global__ __launch_bounds__(256) void emb_mfma(
    const unsigned short* __restrict__ XhF, const unsigned short* __restrict__ XlF,
    const unsigned short* __restrict__ WhF, const unsigned short* __restrict__ WlF,
    unsigned short* __restrict__ ehiF, unsigned short* __restrict__ eloF) {
  __shared__ float lds[4][16][65];
  int lane = threadIdx.x & 63, w = threadIdx.x >> 6;
  int l15 = lane & 15, lg = lane >> 4;
  int rowblk0 = blockIdx.x * 2;            // 32 rows per block
  f32x4 acc[2][4] = {};
  for (int kb = 0; kb < DIN / 32; kb++) {
    bf16x8 ah[2], al[2], bh[4], bl[4];
    #pragma unroll
    for (int fm = 0; fm < 2; fm++) {
      size_t o = (((size_t)(rowblk0 + fm) * (DIN / 32) + kb) * 64 + lane) * 8;
      ah[fm] = *reinterpret_cast<const bf16x8*>(XhF + o);
      al[fm] = *reinterpret_cast<const bf16x8*>(XlF + o);
    }
    #pragma unroll
    for (int fn = 0; fn < 4; fn++) {
      size_t o = (((size_t)(w * 4 + fn) * (DIN / 32) + kb) * 64 + lane) * 8;
      bh[fn] = *reinterpret_cast<const bf16x8*>(WhF + o);
      bl[fn] = *reinterpret_cast<const bf16x8*>(WlF + o);
    }
    #pragma unroll
    for (int fm = 0; fm < 2; fm++)
      #pragma unroll
      for (int fn = 0; fn < 4; fn++) {
        acc[fm][fn] = __builtin_amdgcn_mfma_f32_16x16x32_bf16(ah[fm], bh[fn], acc[fm][fn], 0, 0, 0);
        acc[fm][fn] = __builtin_amdgcn_mfma_f32_16x16x32_bf16(ah[fm], bl[fn], acc[fm][fn], 0, 0, 0);
        acc[fm][fn] = __builtin_amdgcn_mfma_f32_16x16x32_bf16(al[fm], bh[fn], acc[fm][fn], 0, 0, 0);
        acc[fm][fn] = __builtin_amdgcn_mfma_f32_16x16x32_bf16(al[fm], bl[fn], acc[fm][fn], 0, 0, 0);
      }
  }
  // C/D (col=l15,row=lg*4+r) -> fragment-major via LDS permute
  for (int fm = 0; fm < 2; fm++) {
    #pragma unroll
    for (int fn = 0; fn < 4; fn++)
      #pragma unroll
      for (int r = 0; r < 4; r++)
        lds[w][lg * 4 + r][fn * 16 + l15] = acc[fm][fn][r];
    __syncthreads();
    #pragma unroll
    for (int cb = 0; cb < 2; cb++) {
      const float* src = &lds[w][l15][cb * 32 + lg * 8];
      bf16x8 hv, lv;
      #pragma unroll
      for (int j = 0; j < 8; j++) {
        float v = src[j];
        unsigned short h = f2bf(v);
        hv[j] = (short)h;
        lv[j] = (short)f2bf(v - bf2f(h));
      }
      size_t off = (((size_t)(rowblk0 + fm) * (DEMB / 32) + w * 2 + cb) * 64 + lane) * 8;
      *reinterpret_cast<bf16x8*>(ehiF + off) = hv;
      *reinterpret_cast<bf16x8*>(eloF + off) = lv;
    }
    __syncthreads();
  }
}

// ---------- 2) similarity: tri-linearized grid + XCD swizzle -> Apk both triangles ----------
__global__ __launch_bounds__(256) void sim_kernel(
    const unsigned short* __restrict__ ehiF, const unsigned short* __restrict__ eloF,
    unsigned int* __restrict__ Apk) {
  // 2080 upper-tri tiles; bijective XCD swizzle (2080 = 8*260), then inverse-triangular
  int bid = (blockIdx.x & 7) * 260 + (blockIdx.x >> 3);
  int r = 2079 - bid;
  int j = (int)((sqrtf((float)(8 * r + 1)) - 1.0f) * 0.5f);
  while ((j + 1) * (j + 2) / 2 <= r) ++j;
  while (j * (j + 1) / 2 > r) --j;
  int by = 63 - j;
  int bx = 63 - (r - j * (j + 1) / 2);

  __shared__ unsigned short LTn[128][8];     // normal bit-rows (ushort per 16 cols)
  __shared__ unsigned short LTt[128][8];     // transposed
  int lane = threadIdx.x & 63;
  int w = threadIdx.x >> 6, wm = w >> 1, wn = w & 1;
  int l15 = lane & 15, lg = lane >> 4;
  int arb = by * 8 + wm * 4, brb = bx * 8 + wn * 4;

  f32x4 acc[4][4] = {};
  #pragma unroll 2
  for (int kb = 0; kb < DEMB / 32; kb++) {
    bf16x8 bh[4], bl[4];
    #pragma unroll
    for (int fn = 0; fn < 4; fn++) {
      size_t o = (((size_t)(brb + fn) * (DEMB / 32) + kb) * 64 + lane) * 8;
      bh[fn] = *reinterpret_cast<const bf16x8*>(ehiF + o);
      bl[fn] = *reinterpret_cast<const bf16x8*>(eloF + o);
    }
    #pragma unroll
    for (int fm = 0; fm < 4; fm++) {
      size_t o = (((size_t)(arb + fm) * (DEMB / 32) + kb) * 64 + lane) * 8;
      bf16x8 ah = *reinterpret_cast<const bf16x8*>(ehiF + o);
      bf16x8 al = *reinterpret_cast<const bf16x8*>(eloF + o);
      #pragma unroll
      for (int fn = 0; fn < 4; fn++) {
        acc[fm][fn] = __builtin_amdgcn_mfma_f32_16x16x32_bf16(ah, bh[fn], acc[fm][fn], 0, 0, 0);
        acc[fm][fn] = __builtin_amdgcn_mfma_f32_16x16x32_bf16(ah, bl[fn], acc[fm][fn], 0, 0, 0);
        acc[fm][fn] = __builtin_amdgcn_mfma_f32_16x16x32_bf16(al, bh[fn], acc[fm][fn], 0, 0, 0);
      }
    }
  }
  // threshold + ballot -> LTn only
  #pragma unroll
  for (int fm = 0; fm < 4; fm++)
    #pragma unroll
    for (int fn = 0; fn < 4; fn++)
      #pragma unroll
      for (int r4 = 0; r4 < 4; r4++) {
        unsigned long long bal = __ballot(acc[fm][fn][r4] > 0.5f);
        if (l15 == 0)
          LTn[wm * 64 + fm * 16 + lg * 4 + r4][wn * 4 + fn] =
              (unsigned short)(bal >> (lg * 16));
      }
  __syncthreads();
  // 16x16 bit-transpose LTn -> LTt, one tile per thread (64 tiles)
  if (threadIdx.x < 64) {
    int tr = threadIdx.x >> 3, tc = threadIdx.x & 7;
    unsigned int m[16], t;
    #pragma unroll
    for (int q = 0; q < 16; q++) m[q] = LTn[tr * 16 + q][tc];
    #pragma unroll
    for (int i = 0; i < 8; i++) { t = ((m[i] >> 8) ^ m[i + 8]) & 0x00FFu; m[i + 8] ^= t; m[i] ^= t << 8; }
    #pragma unroll
    for (int g = 0; g < 16; g += 8)
      #pragma unroll
      for (int i = g; i < g + 4; i++) { t = ((m[i] >> 4) ^ m[i + 4]) & 0x0F0Fu; m[i + 4] ^= t; m[i] ^= t << 4; }
    #pragma unroll
    for (int g = 0; g < 16; g += 4)
      #pragma unroll
      for (int i = g; i < g + 2; i++) { t = ((m[i] >> 2) ^ m[i + 2]) & 0x3333u; m[i + 2] ^= t; m[i] ^= t << 2; }
    #pragma unroll
    for (int g = 0; g < 16; g += 2) { t = ((m[g] >> 1) ^ m[g + 1]) & 0x5555u; m[g + 1] ^= t; m[g] ^= t << 1; }
    #pragma unroll
    for (int q = 0; q < 16; q++) LTt[tc * 16 + q][tr] = (unsigned short)m[q];
  }
  __syncthreads();
  // assemble Apk dwords: dword(rowblk,S4,lane={row&15,lg}) byte t = bits k=S4*128+t*32+lg*8
  #pragma unroll
  for (int pass = 0; pass < 2; pass++) {
    int idx = pass * 256 + threadIdx.x;      // 0..511
    int rb4 = idx >> 6, ln = idx & 63;
    int lr = rb4 * 16 + (ln & 15), Lg = ln >> 4;
    unsigned int d = 0, d2 = 0;
    #pragma unroll
    for (int t = 0; t < 4; t++) {
      int bix = t * 4 + Lg;
      unsigned int u = LTn[lr][bix >> 1];
      d |= ((u >> ((bix & 1) * 8)) & 0xffu) << (t * 8);
      unsigned int u2 = LTt[lr][bix >> 1];
      d2 |= ((u2 >> ((bix & 1) * 8)) & 0xffu) << (t * 8);
    }
    Apk[((size_t)(by * 8 + rb4) * 64 + bx) * 64 + ln] = d;
    Apk[((size_t)(bx * 8 + rb4) * 64 + by) * 64 + ln] = d2;
  }
}

// ---------- 3) rdeg = 1/popcount, straight from Apk (coalesced) ----------
__global__ __launch_bounds__(256) void degree_kernel(
    const unsigned int* __restrict__ Apk, float* __restrict__ rdeg) {
  __shared__ int dg[4][16];
  int rowblk = blockIdx.x;
  int w = threadIdx.x >> 6, lane = threadIdx.x & 63;
  const unsigned int* base = Apk + (size_t)rowblk * 4096;
  int cnt = 0;
  #pragma unroll
  for (int s = 0; s < 16; s++) cnt += __popc(base[(w * 16 + s) * 64 + lane]);
  cnt += __shfl_xor(cnt, 16);
  cnt += __shfl_xor(cnt, 32);
  if (lane < 16) dg[w][lane] = cnt;
  __syncthreads();
  if (threadIdx.x < 16) {
    int c = dg[0][threadIdx.x] + dg[1][threadIdx.x] + dg[2][threadIdx.x] + dg[3][threadIdx.x];
    rdeg[rowblk * 16 + threadIdx.x] = (c == 0) ? 1.f : 1.f / (float)c;
  }
}

// ---------- 4) label init: support one-hot, query zero ----------
__global__ __launch_bounds__(256) void init_labels(
    const int* __restrict__ slab, float* __restrict__ labels,
    unsigned short* __restrict__ LtF) {
  int idx = blockIdx.x * 256 + threadIdx.x;
  int i = idx >> 6, c = idx & 63;
  float v = 0.f;
  if (i < NSUP && slab[i] == c) v = 1.f;
  labels[idx] = v;
  LtF[lfrag(i, c)] = f2bf(v);
}

// ---------- 5) fused prop: 256 blocks x 32 rows, full K in-kernel, no Cpart ----------
// 8 waves; wave wk = 2 rowblks x 1024-K chunk; 8-way wk-reduce in LDS; fused epilogue.
#define RED(k, row, col) red[k][row][(col) ^ ((((row) >> 2) & 3) << 4)]
__global__ __launch_bounds__(512) void prop_fused(
    const unsigned int* __restrict__ Apk, const unsigned short* __restrict__ LtinF,
    const float* __restrict__ rdeg, float* __restrict__ labels,
    unsigned short* __restrict__ LtoutF, float* __restrict__ outq, int last) {
  __shared__ float red[8][32][64];          // 64 KB
  __shared__ unsigned short stile[2048];    // 4 KB lfrag-local out tile
  int lane = threadIdx.x & 63;
  int wk = threadIdx.x >> 6;
  int l15 = lane & 15, lg = lane >> 4;
  int rg = blockIdx.x;                      // 32 rows: rowblks rg*2, rg*2+1
  int rb0 = rg * 2;
  int s4base = wk * 8;                      // 8 S4 units = 1024 K per wave

  f32x4 acc[2][4] = {};
  #pragma unroll 2
  for (int s4 = 0; s4 < 8; s4++) {
    unsigned int ad[2];
    ad[0] = Apk[((size_t)rb0 * 64 + s4base + s4) * 64 + lane];
    ad[1] = Apk[((size_t)(rb0 + 1) * 64 + s4base + s4) * 64 + lane];
    #pragma unroll
    for (int t = 0; t < 4; t++) {
      int kstep = (s4base + s4) * 4 + t;
      bf16x8 b[4];
      #pragma unroll
      for (int fn = 0; fn < 4; fn++)
        b[fn] = *reinterpret_cast<const bf16x8*>(
            LtinF + (((size_t)kstep * 4 + fn) * 64 + lane) * 8);
      #pragma unroll
      for (int rb = 0; rb < 2; rb++) {
        unsigned int bb = (ad[rb] >> (8 * t)) & 0xffu;
        u32x4 uu;
        uu.x = ((bb & 1u)   ? 0x3F80u : 0u) | ((bb & 2u)   ? 0x3F800000u : 0u);
        uu.y = ((bb & 4u)   ? 0x3F80u : 0u) | ((bb & 8u)   ? 0x3F800000u : 0u);
        uu.z = ((bb & 16u)  ? 0x3F80u : 0u) | ((bb & 32u)  ? 0x3F800000u : 0u);
        uu.w = ((bb & 64u)  ? 0x3F80u : 0u) | ((bb & 128u) ? 0x3F800000u : 0u);
        bf16x8 a = __builtin_bit_cast(bf16x8, uu);
        #pragma unroll
        for (int fn = 0; fn < 4; fn++)
          acc[rb][fn] = __builtin_amdgcn_mfma_f32_16x16x32_bf16(a, b[fn], acc[rb][fn], 0, 0, 0);
      }
    }
  }
  // single-pass 8-way reduce staging
  #pragma unroll
  for (int rb = 0; rb < 2; rb++)
    #pragma unroll
    for (int fn = 0; fn < 4; fn++)
      #pragma unroll
      for (int r4 = 0; r4 < 4; r4++)
        RED(wk, rb * 16 + lg * 4 + r4, fn * 16 + l15) = acc[rb][fn][r4];
  __syncthreads();
  // fused epilogue: thread = (row 0..31, 4 cols)
  {
    int row = threadIdx.x >> 4;              // 0..31
    int c0 = (threadIdx.x & 15) * 4;
    float s[4] = {0.f, 0.f, 0.f, 0.f};
    #pragma unroll
    for (int k = 0; k < 8; k++)
      #pragma unroll
      for (int jj = 0; jj < 4; jj++)
        s[jj] += RED(k, row, c0 + jj);
    int grow = rg * 32 + row;
    size_t idx = (size_t)grow * NCLS + c0;
    float rd = 0.5f * rdeg[grow];
    float4 l = *reinterpret_cast<const float4*>(labels + idx);
    float v0 = 0.5f * l.x + s[0] * rd, v1 = 0.5f * l.y + s[1] * rd;
    float v2 = 0.5f * l.z + s[2] * rd, v3 = 0.5f * l.w + s[3] * rd;
    float4 o = make_float4(v0, v1, v2, v3);
    *reinterpret_cast<float4*>(labels + idx) = o;
    if (last && grow >= NSUP)
      *reinterpret_cast<float4*>(outq + idx - (size_t)NSUP * NCLS) = o;
    // stage bf16 lfrag-local: off = (c>>4)*512 + ((c&15)+16*((row>>3)&3))*8 + (row&7)
    int sb = (c0 >> 4) * 512 + ((row >> 3) & 3) * 128 + (row & 7);
    stile[sb + ((c0 & 15) + 0) * 8] = f2bf(v0);
    stile[sb + ((c0 & 15) + 1) * 8] = f2bf(v1);
    stile[sb + ((c0 & 15) + 2) * 8] = f2bf(v2);
    stile[sb + ((c0 & 15) + 3) * 8] = f2bf(v3);
  }
  __syncthreads();
  // stream out: one contiguous 4 KB run (i-block rg)
  if (threadIdx.x < 256)
    *reinterpret_cast<bf16x8*>(LtoutF + (size_t)rg * 2048 + threadIdx.x * 8) =
        *reinterpret_cast<const bf16x8*>(&stile[threadIdx.x * 8]);
}

extern "C" void kernel_launch(void* const* d_in, const int* in_sizes, int n_in,
                              void* d_out, int out_size, void* d_ws, size_t ws_size,
                              hipStream_t stream) {
  const float* support = (const float*)d_in[0];
  const float* query   = (const float*)d_in[1];
  const float* W       = (const float*)d_in[2];
  const int*   slab    = (const int*)d_in[3];
  float* out = (float*)d_out;
  char* ws = (char*)d_ws;
  const size_t MB = (size_t)1 << 20;
  // Apk aliases XhF (dead after emb_mfma).
  unsigned short* XhF    = (unsigned short*)(ws);            // 8 MB
  unsigned int*   Apk    = (unsigned int*)(ws);              // 8 MB (alias)
  unsigned short* XlF    = (unsigned short*)(ws + 8 * MB);   // 8 MB
  unsigned short* ehiF   = (unsigned short*)(ws + 24 * MB);  // 4 MB
  unsigned short* eloF   = (unsigned short*)(ws + 28 * MB);  // 4 MB
  unsigned short* WhF    = (unsigned short*)(ws + 32 * MB);  // 256 KB
  unsigned short* WlF    = (unsigned short*)(ws + 32 * MB + 256 * 1024); // 256 KB
  float*          labels = (float*)(ws + 33 * MB);           // 2 MB fp32 [8192][64]
  unsigned short* Lt0    = (unsigned short*)(ws + 35 * MB);  // 1 MB frag-major
  unsigned short* Lt1    = (unsigned short*)(ws + 36 * MB);  // 1 MB
  float*          rdeg   = (float*)(ws + 37 * MB);           // 32 KB

  splitX<<<NTOT / 4, 256, 0, stream>>>(support, query, XhF, XlF);
  splitW<<<DIN * DEMB / 8 / 256, 256, 0, stream>>>(W, WhF, WlF);
  emb_mfma<<<NTOT / 32, 256, 0, stream>>>(XhF, XlF, WhF, WlF, ehiF, eloF);
  sim_kernel<<<2080, 256, 0, stream>>>(ehiF, eloF, Apk);
  degree_kernel<<<NTOT / 16, 256, 0, stream>>>(Apk, rdeg);
  init_labels<<<NTOT * NCLS / 256, 256, 0, stream>>>(slab, labels, Lt0);
  for (int t = 0; t < 10; t++) {
    unsigned short* Li = (t & 1) ? Lt1 : Lt0;
    unsigned short* Lo = (t & 1) ? Lt0 : Lt1;
    prop_fused<<<NTOT / 32, 512, 0, stream>>>(Apk, Li, rdeg, labels, Lo, out, (t == 9) ? 1 : 0);
  }
}